// Round 1
// baseline (191.620 us; speedup 1.0000x reference)
//
#include <hip/hip_runtime.h>

#define FEATS 64
#define HSZ   4096
#define ISZ   12480          // (FEATS+1)*FEATS*3
#define I4    (ISZ/4)        // 3120 float4
#define H4    (HSZ/4)        // 1024 float4

// workspace layout (float offsets)
#define X_OFF  0             // 12480
#define HF_OFF 12480         // 4096  (h_f rows 1..64)
#define HT_OFF 16576         // 4096  (h_t rows 1..64)
#define GI_OFF 20672         // 12288
#define GH_OFF 32960         // 12288
// total 45248 floats = ~177 KB of ws

#define GI_BLOCKS 384
#define GH_BLOCKS 128
#define B_THREADS 512

// ---------------- A1: the two 64x64 GAT matmuls (rows 1..64 only; row 0 is zero) ----
__global__ void gat_matmul(const float* __restrict__ data,
                           const float* __restrict__ fW,
                           const float* __restrict__ tW,
                           float* __restrict__ ws) {
    int idx   = blockIdx.x * 256 + threadIdx.x;   // 0..8191
    int which = idx >> 12;                        // 0: feat GAT, 1: time GAT
    int o     = idx & 4095;
    int v     = o >> 6;                           // node v+1
    int j     = o & 63;                           // head
    const float* W = which ? tW : fW;
    float acc = 0.f;
    if (which == 0) {
        #pragma unroll 8
        for (int k = 0; k < 64; ++k) acc += data[v*64 + k] * W[k*64 + j];
    } else {
        #pragma unroll 8
        for (int k = 0; k < 64; ++k) acc += data[k*64 + v] * W[k*64 + j];
    }
    ws[(which ? HT_OFF : HF_OFF) + o] = acc;
}

// ---------------- A2: softmax over the 65-node star + assemble GRU input x ----------
__global__ void gat_softmax_assemble(const float* __restrict__ data,
                                     const float* __restrict__ fal,
                                     const float* __restrict__ fb,
                                     const float* __restrict__ tal,
                                     const float* __restrict__ tb,
                                     float* __restrict__ ws) {
    __shared__ float s_out0[2][64];
    int tid = threadIdx.x;
    if (tid < 128) {
        int which = tid >> 6;
        int j     = tid & 63;
        const float* h = ws + (which ? HT_OFF : HF_OFF);
        float al = which ? tal[j] : fal[j];
        // e[v] = leaky_relu(h[v]*al[j]) ; e[0] = 0 (h[0]=0, er[0]=0)
        float m = 0.f;
        for (int v = 0; v < 64; ++v) {
            float hv = h[v*64 + j];
            float e  = hv * al;
            e = e > 0.f ? e : 0.2f * e;
            m = fmaxf(m, e);
        }
        float sum = expf(0.f - m);   // node-0 term (h=0 contributes 0 to numerator)
        float num = 0.f;
        for (int v = 0; v < 64; ++v) {
            float hv = h[v*64 + j];
            float e  = hv * al;
            e = e > 0.f ? e : 0.2f * e;
            float a = expf(e - m);
            sum += a;
            num += a * hv;
        }
        s_out0[which][j] = num / sum;
    }
    __syncthreads();
    // x[(n*64+f)*3 + c]: c0 = data_r, c1 = feat_r + fb, c2 = time_r + tb
    for (int idx = tid; idx < ISZ; idx += blockDim.x) {
        int c  = idx % 3;
        int nf = idx / 3;
        int n  = nf >> 6;
        int f  = nf & 63;
        float val;
        if (c == 0)      val = (n == 0) ? 0.f : data[(n-1)*64 + f];
        else if (c == 1) val = ((n == 0) ? s_out0[0][f] : ws[HF_OFF + (n-1)*64 + f]) + fb[f];
        else             val = ((n == 0) ? s_out0[1][f] : ws[HT_OFF + (n-1)*64 + f]) + tb[f];
        ws[X_OFF + idx] = val;
    }
}

// ---------------- B: the two big matvecs (memory-bound; 815 MB of weights) ---------
__device__ __forceinline__ float wave_reduce(float v) {
    #pragma unroll
    for (int off = 32; off > 0; off >>= 1) v += __shfl_down(v, off);
    return v;
}

__global__ __launch_bounds__(B_THREADS, 4)
void big_matvec(const float* __restrict__ W_ih,
                const float* __restrict__ W_hh,
                const float* __restrict__ h0,
                float* __restrict__ ws) {
    __shared__ float4 vec[I4];                    // 49,920 B
    int b    = blockIdx.x;
    int tid  = threadIdx.x;
    int wave = tid >> 6;
    int lane = tid & 63;

    if (b < GI_BLOCKS) {
        const float4* x4 = (const float4*)(ws + X_OFF);
        for (int k = tid; k < I4; k += B_THREADS) vec[k] = x4[k];
        __syncthreads();
        int base = b * (3 * HSZ / GI_BLOCKS);     // 32 rows per block
        for (int r0 = wave; r0 < 3 * HSZ / GI_BLOCKS; r0 += B_THREADS / 64) {
            int r = base + r0;
            const float4* Wr = (const float4*)(W_ih + (size_t)r * ISZ);
            float acc = 0.f;
            for (int k = lane; k < I4; k += 64) {
                float4 w = Wr[k];
                float4 v = vec[k];
                acc += w.x*v.x + w.y*v.y + w.z*v.z + w.w*v.w;
            }
            acc = wave_reduce(acc);
            if (lane == 0) ws[GI_OFF + r] = acc;
        }
    } else {
        const float4* h4 = (const float4*)h0;
        for (int k = tid; k < H4; k += B_THREADS) vec[k] = h4[k];
        __syncthreads();
        int bb   = b - GI_BLOCKS;
        int base = bb * (3 * HSZ / GH_BLOCKS);    // 96 rows per block
        for (int r0 = wave; r0 < 3 * HSZ / GH_BLOCKS; r0 += B_THREADS / 64) {
            int r = base + r0;
            const float4* Wr = (const float4*)(W_hh + (size_t)r * HSZ);
            float acc = 0.f;
            for (int k = lane; k < H4; k += 64) {
                float4 w = Wr[k];
                float4 v = vec[k];
                acc += w.x*v.x + w.y*v.y + w.z*v.z + w.w*v.w;
            }
            acc = wave_reduce(acc);
            if (lane == 0) ws[GH_OFF + r] = acc;
        }
    }
}

// ---------------- C: GRU gate math + write both output copies ----------------------
__global__ void gru_combine(const float* __restrict__ h0,
                            const float* __restrict__ b_ih,
                            const float* __restrict__ b_hh,
                            const float* __restrict__ ws,
                            float* __restrict__ out) {
    int j = blockIdx.x * 256 + threadIdx.x;
    if (j >= HSZ) return;
    const float* gi = ws + GI_OFF;
    const float* gh = ws + GH_OFF;
    float ir  = gi[j]           + b_ih[j];
    float iz  = gi[HSZ + j]     + b_ih[HSZ + j];
    float in_ = gi[2*HSZ + j]   + b_ih[2*HSZ + j];
    float hr  = gh[j]           + b_hh[j];
    float hz  = gh[HSZ + j]     + b_hh[HSZ + j];
    float hn  = gh[2*HSZ + j]   + b_hh[2*HSZ + j];
    float r = 1.f / (1.f + expf(-(ir + hr)));
    float z = 1.f / (1.f + expf(-(iz + hz)));
    float n = tanhf(in_ + r * hn);
    float h = (1.f - z) * n + z * h0[j];
    out[j]       = h;
    out[HSZ + j] = h;
}

extern "C" void kernel_launch(void* const* d_in, const int* in_sizes, int n_in,
                              void* d_out, int out_size, void* d_ws, size_t ws_size,
                              hipStream_t stream) {
    const float* data   = (const float*)d_in[0];
    const float* hidden = (const float*)d_in[1];
    const float* fgat_W = (const float*)d_in[2];
    const float* fgat_al= (const float*)d_in[3];
    // d_in[4] = fgat_ar (unused: er[0] = h[0]*ar = 0 since padded row 0 is zero)
    const float* fgat_b = (const float*)d_in[5];
    const float* tgat_W = (const float*)d_in[6];
    const float* tgat_al= (const float*)d_in[7];
    // d_in[8] = tgat_ar (unused, same reason)
    const float* tgat_b = (const float*)d_in[9];
    const float* W_ih   = (const float*)d_in[10];
    const float* W_hh   = (const float*)d_in[11];
    const float* b_ih   = (const float*)d_in[12];
    const float* b_hh   = (const float*)d_in[13];
    float* ws  = (float*)d_ws;
    float* out = (float*)d_out;

    gat_matmul<<<32, 256, 0, stream>>>(data, fgat_W, tgat_W, ws);
    gat_softmax_assemble<<<1, 256, 0, stream>>>(data, fgat_al, fgat_b,
                                                tgat_al, tgat_b, ws);
    big_matvec<<<GI_BLOCKS + GH_BLOCKS, B_THREADS, 0, stream>>>(W_ih, W_hh, hidden, ws);
    gru_combine<<<(HSZ + 255) / 256, 256, 0, stream>>>(hidden, b_ih, b_hh, ws, out);
}